// Round 3
// baseline (840.875 us; speedup 1.0000x reference)
//
#include <hip/hip_runtime.h>
#include <stdint.h>

#define NUM_CHARS 128
#define BATCH 8192
#define SEQ 40
#define HIDDEN 256
#define ZDIM 1024 /* 4*HIDDEN */
#define STRIDE_H 264 /* padded bf16 row stride for h in LDS */

typedef __bf16 bf16x8 __attribute__((ext_vector_type(8)));
typedef float floatx16 __attribute__((ext_vector_type(16)));

__device__ __forceinline__ unsigned short f2bf(float f) {
    union { float f; uint32_t u; } v; v.f = f;
    uint32_t u = v.u;
    u += 0x7FFFu + ((u >> 16) & 1u); // RNE
    return (unsigned short)(u >> 16);
}

// ---- prep kernels: repack weights into MFMA-fragment-contiguous layouts ----
// WhFrag[ntile(32)][kk(16)][lane(64)][j(8)] bf16 ; element = Wh[k][n],
// k = kk*16 + (lane>>5)*8 + j, n = ntile*32 + (lane&31)
__global__ void prep_wh(const float* __restrict__ Wh, unsigned short* __restrict__ out) {
    int idx = blockIdx.x * blockDim.x + threadIdx.x; // 0..262143
    int j = idx & 7;
    int lane = (idx >> 3) & 63;
    int kk = (idx >> 9) & 15;
    int ntile = idx >> 13;
    int k = kk * 16 + ((lane >> 5) << 3) + j;
    int n = (ntile << 5) + (lane & 31);
    out[idx] = f2bf(Wh[k * ZDIM + n]);
}

__global__ void prep_wxb(const float* __restrict__ Wx, const float* __restrict__ b,
                         float* __restrict__ out) {
    int idx = blockIdx.x * blockDim.x + threadIdx.x; // 0..131071
    out[idx] = Wx[idx] + b[idx & (ZDIM - 1)];
}

// WdFrag[ntile(4)][kk(16)][lane(64)][j(8)] bf16 ; element = Wd[k][n]
__global__ void prep_wd(const float* __restrict__ Wd, unsigned short* __restrict__ out) {
    int idx = blockIdx.x * blockDim.x + threadIdx.x; // 0..32767
    int j = idx & 7;
    int lane = (idx >> 3) & 63;
    int kk = (idx >> 9) & 15;
    int nt = idx >> 13;
    int k = kk * 16 + ((lane >> 5) << 3) + j;
    int n = (nt << 5) + (lane & 31);
    out[idx] = f2bf(Wd[k * NUM_CHARS + n]);
}

// ---- main kernel: 256 blocks x 512 threads; block owns 32 batch rows ----
__global__ __launch_bounds__(512, 2) void lstm_main(
    const int* __restrict__ inputs, const unsigned short* __restrict__ WhFrag,
    const float* __restrict__ WxB, const unsigned short* __restrict__ WdFrag,
    const float* __restrict__ bd, float* __restrict__ out)
{
    __shared__ unsigned short hbuf[32 * STRIDE_H];   // 16.5 KB, single-buffered h
    __shared__ unsigned short whlds[32 * 64 * 8];    // 32 KB: Wh kk=0 slice, all 32 ntiles
    __shared__ int tok[32 * SEQ];                    //  5.1 KB
    float* logit = (float*)&whlds[0];                // 16 KB epilogue overlay

    const int tid = threadIdx.x;
    const int w = tid >> 6;        // wave 0..7, owns z-cols g*256 + [w*32, w*32+32)
    const int lane = tid & 63;
    const int r0 = blockIdx.x * 32;

    for (int i = tid; i < 32 * SEQ; i += 512) tok[i] = inputs[r0 * SEQ + i];
    for (int i = tid; i < 32 * STRIDE_H; i += 512) hbuf[i] = 0;
    // whlds <- WhFrag slice kk=0: dst[ntile*512 + lane*8 + j] = WhFrag[ntile*8192 + lane*8 + j]
    for (int i = tid; i < 2048; i += 512)
        ((uint4*)whlds)[i] = *(const uint4*)(WhFrag + ((i >> 6) * 8192 + (i & 63) * 8));

    // C/D layout: col = lane&31, row = (reg&3) + 8*(reg>>2) + 4*(lane>>5)
    int rows[16];
#pragma unroll
    for (int i = 0; i < 16; ++i) rows[i] = (i & 3) + 8 * (i >> 2) + 4 * (lane >> 5);

    floatx16 c_st;
#pragma unroll
    for (int i = 0; i < 16; ++i) c_st[i] = 0.f;

    __syncthreads();

    const float L2E = 1.4426950408889634f;
    const int abase = (lane & 31) * STRIDE_H + ((lane >> 5) << 3);
    const int hcol = (w << 5) + (lane & 31);
    // frag (ntile,kk) lives at WhFrag[(ntile*16+kk)*512 + lane*8]; ntile(g) = g*8+w
    const unsigned short* sgb[4];
#pragma unroll
    for (int g = 0; g < 4; ++g) sgb[g] = WhFrag + (g * 8 + w) * 8192 + lane * 8;

#pragma unroll 1
    for (int t = 0; t < SEQ; ++t) {
        // ---- issue gather of Wx[token]+b now; consumed ~8k cycles later at gates ----
        int toff[16];
#pragma unroll
        for (int i = 0; i < 16; ++i) toff[i] = tok[rows[i] * SEQ + t] << 10;
        float gx[4][16];
#pragma unroll
        for (int g = 0; g < 4; ++g) {
            int col = (g << 8) + hcol;
#pragma unroll
            for (int i = 0; i < 16; ++i) gx[g][i] = WxB[toff[i] + col];
        }

        // ---- h @ Wh from C=0; kk=0 B-frags from LDS, kk=1..15 streamed from L2 ----
        floatx16 acc[4];
#pragma unroll
        for (int g = 0; g < 4; ++g)
#pragma unroll
            for (int i = 0; i < 16; ++i) acc[g][i] = 0.f;

        {
            bf16x8 af0 = *(const bf16x8*)(hbuf + abase);
#pragma unroll
            for (int g = 0; g < 4; ++g) {
                bf16x8 bf0 = *(const bf16x8*)(whlds + (g * 8 + w) * 512 + lane * 8);
                acc[g] = __builtin_amdgcn_mfma_f32_32x32x16_bf16(af0, bf0, acc[g], 0, 0, 0);
            }
        }
        bf16x8 wv[2][4];
#pragma unroll
        for (int g = 0; g < 4; ++g) {
            wv[0][g] = *(const bf16x8*)(sgb[g] + (1 << 9));
            wv[1][g] = *(const bf16x8*)(sgb[g] + (2 << 9));
        }
#pragma unroll
        for (int kk = 1; kk < 16; ++kk) {
            const int s = (kk - 1) & 1;
            bf16x8 af = *(const bf16x8*)(hbuf + abase + kk * 16);
            acc[0] = __builtin_amdgcn_mfma_f32_32x32x16_bf16(af, wv[s][0], acc[0], 0, 0, 0);
            acc[1] = __builtin_amdgcn_mfma_f32_32x32x16_bf16(af, wv[s][1], acc[1], 0, 0, 0);
            acc[2] = __builtin_amdgcn_mfma_f32_32x32x16_bf16(af, wv[s][2], acc[2], 0, 0, 0);
            acc[3] = __builtin_amdgcn_mfma_f32_32x32x16_bf16(af, wv[s][3], acc[3], 0, 0, 0);
            if (kk + 2 < 16) {
#pragma unroll
                for (int g = 0; g < 4; ++g)
                    wv[s][g] = *(const bf16x8*)(sgb[g] + ((kk + 2) << 9));
            }
        }

        // ---- gates (keras i,f,g,o); z = acc + gx; c fp32 in regs ----
        float ho[16];
#pragma unroll
        for (int i = 0; i < 16; ++i) {
            float zi = acc[0][i] + gx[0][i];
            float zf = acc[1][i] + gx[1][i];
            float zg = acc[2][i] + gx[2][i];
            float zo = acc[3][i] + gx[3][i];
            float si = __builtin_amdgcn_rcpf(1.f + __builtin_amdgcn_exp2f(-zi * L2E));
            float sf = __builtin_amdgcn_rcpf(1.f + __builtin_amdgcn_exp2f(-zf * L2E));
            float so = __builtin_amdgcn_rcpf(1.f + __builtin_amdgcn_exp2f(-zo * L2E));
            float tg = 1.f - 2.f * __builtin_amdgcn_rcpf(1.f + __builtin_amdgcn_exp2f(2.f * L2E * zg));
            float c = sf * c_st[i] + si * tg;
            c_st[i] = c;
            float tc = 1.f - 2.f * __builtin_amdgcn_rcpf(1.f + __builtin_amdgcn_exp2f(2.f * L2E * c));
            ho[i] = so * tc;
        }
        __syncthreads();   // all waves done reading old h
#pragma unroll
        for (int i = 0; i < 16; ++i)
            hbuf[rows[i] * STRIDE_H + hcol] = f2bf(ho[i]);
        __syncthreads();   // new h visible
    }

    // ---- logits = h @ Wd + bd (waves 0..3, vocab n-tile = w); overlay whlds ----
    if (w < 4) {
        floatx16 accd;
        float bdv = bd[(w << 5) + (lane & 31)];
#pragma unroll
        for (int i = 0; i < 16; ++i) accd[i] = bdv;
#pragma unroll
        for (int kk = 0; kk < 16; ++kk) {
            bf16x8 af = *(const bf16x8*)(hbuf + abase + kk * 16);
            bf16x8 bfd = *(const bf16x8*)(WdFrag + ((w * 16 + kk) << 9) + lane * 8);
            accd = __builtin_amdgcn_mfma_f32_32x32x16_bf16(af, bfd, accd, 0, 0, 0);
        }
#pragma unroll
        for (int i = 0; i < 16; ++i)
            logit[rows[i] * NUM_CHARS + (w << 5) + (lane & 31)] = accd[i];
    }
    __syncthreads();

    // ---- softmax: 16 threads per row, 8 cols each ----
    {
        int row = tid >> 4;
        int c0 = (tid & 15) << 3;
        float v[8];
        float m = -1e30f;
#pragma unroll
        for (int q = 0; q < 8; ++q) { v[q] = logit[row * NUM_CHARS + c0 + q]; m = fmaxf(m, v[q]); }
#pragma unroll
        for (int off = 1; off < 16; off <<= 1) m = fmaxf(m, __shfl_xor(m, off, 16));
        float s = 0.f;
#pragma unroll
        for (int q = 0; q < 8; ++q) { v[q] = __builtin_amdgcn_exp2f((v[q] - m) * L2E); s += v[q]; }
#pragma unroll
        for (int off = 1; off < 16; off <<= 1) s += __shfl_xor(s, off, 16);
        float inv = __builtin_amdgcn_rcpf(s);
        float* op = out + (size_t)(r0 + row) * NUM_CHARS + c0;
#pragma unroll
        for (int q = 0; q < 8; ++q) op[q] = v[q] * inv;
    }
}

extern "C" void kernel_launch(void* const* d_in, const int* in_sizes, int n_in,
                              void* d_out, int out_size, void* d_ws, size_t ws_size,
                              hipStream_t stream) {
    const int*   inputs = (const int*)d_in[0];
    const float* Wx = (const float*)d_in[1];
    const float* Wh = (const float*)d_in[2];
    const float* b  = (const float*)d_in[3];
    const float* Wd = (const float*)d_in[4];
    const float* bd = (const float*)d_in[5];
    float* out = (float*)d_out;

    unsigned short* WhFrag = (unsigned short*)d_ws;                         // 512 KB
    float*          WxB    = (float*)((char*)d_ws + (512 << 10));           // 512 KB
    unsigned short* WdFrag = (unsigned short*)((char*)d_ws + (1024 << 10)); // 64 KB

    prep_wh <<<262144 / 256, 256, 0, stream>>>(Wh, WhFrag);
    prep_wxb<<<131072 / 256, 256, 0, stream>>>(Wx, b, WxB);
    prep_wd <<< 32768 / 256, 256, 0, stream>>>(Wd, WdFrag);
    lstm_main<<<256, 512, 0, stream>>>(inputs, WhFrag, WxB, WdFrag, bd, out);
}

// Round 4
// 599.303 us; speedup vs baseline: 1.4031x; 1.4031x over previous
//
#include <hip/hip_runtime.h>
#include <stdint.h>

#define NUM_CHARS 128
#define BATCH 8192
#define SEQ 40
#define HIDDEN 256
#define ZDIM 1024 /* 4*HIDDEN */
#define STRIDE_H 264 /* padded bf16 row stride for h in LDS */
#define LKK 3      /* K-slices served from LDS (kk = 0..LKK-1) */
#define RKK 13     /* K-slices register-resident (kk = LKK..15) */

typedef __bf16 bf16x8 __attribute__((ext_vector_type(8)));
typedef float floatx16 __attribute__((ext_vector_type(16)));

__device__ __forceinline__ unsigned short f2bf(float f) {
    union { float f; uint32_t u; } v; v.f = f;
    uint32_t u = v.u;
    u += 0x7FFFu + ((u >> 16) & 1u); // RNE
    return (unsigned short)(u >> 16);
}
__device__ __forceinline__ float bfhi(uint32_t u) { // high 16 bits as bf16
    union { uint32_t u; float f; } v; v.u = u & 0xFFFF0000u; return v.f;
}
__device__ __forceinline__ float bflo(uint32_t u) { // low 16 bits as bf16
    union { uint32_t u; float f; } v; v.u = u << 16; return v.f;
}

// ---- prep kernels ----
// WhFrag[ntile(32)][kk(16)][lane(64)][j(8)] bf16 ; element = Wh[k][n],
// k = kk*16 + (lane>>5)*8 + j, n = ntile*32 + (lane&31)
__global__ void prep_wh(const float* __restrict__ Wh, unsigned short* __restrict__ out) {
    int idx = blockIdx.x * blockDim.x + threadIdx.x; // 0..262143
    int j = idx & 7;
    int lane = (idx >> 3) & 63;
    int kk = (idx >> 9) & 15;
    int ntile = idx >> 13;
    int k = kk * 16 + ((lane >> 5) << 3) + j;
    int n = (ntile << 5) + (lane & 31);
    out[idx] = f2bf(Wh[k * ZDIM + n]);
}

// WxBp[v][c(256)][g(4)] bf16, gate-interleaved: one thread's 4 gate values = 8 B
__global__ void prep_wxb(const float* __restrict__ Wx, const float* __restrict__ b,
                         unsigned short* __restrict__ out) {
    int idx = blockIdx.x * blockDim.x + threadIdx.x; // 0..131071
    int v = idx >> 10;
    int r = idx & 1023;
    int c = r >> 2, g = r & 3;
    int src = (g << 8) + c;
    out[idx] = f2bf(Wx[(v << 10) + src] + b[src]);
}

// WdFrag[ntile(4)][kk(16)][lane(64)][j(8)] bf16 ; element = Wd[k][n]
__global__ void prep_wd(const float* __restrict__ Wd, unsigned short* __restrict__ out) {
    int idx = blockIdx.x * blockDim.x + threadIdx.x; // 0..32767
    int j = idx & 7;
    int lane = (idx >> 3) & 63;
    int kk = (idx >> 9) & 15;
    int nt = idx >> 13;
    int k = kk * 16 + ((lane >> 5) << 3) + j;
    int n = (nt << 5) + (lane & 31);
    out[idx] = f2bf(Wd[k * NUM_CHARS + n]);
}

// ---- main kernel: 256 blocks x 512 threads (1 block/CU, 8 waves) ----
// launch_bounds(512,1): full 512-entry unified VGPR+AGPR file per wave.
// Grid == CU count, so this costs no occupancy (measured 23.5% in r1-r3 anyway).
__global__ __launch_bounds__(512, 1) void lstm_main(
    const int* __restrict__ inputs, const unsigned short* __restrict__ WhFrag,
    const unsigned short* __restrict__ WxBp, const unsigned short* __restrict__ WdFrag,
    const float* __restrict__ bd, float* __restrict__ out)
{
    __shared__ unsigned short hbuf[2][32 * STRIDE_H];   // 33.8 KB, double-buffered h
    __shared__ unsigned short whlds[LKK * 32 * 512];    // 96 KB: Wh slices kk=0..2
    __shared__ int tok[32 * SEQ];                       //  5.1 KB
    float* logit = (float*)&whlds[0];                   // 16 KB epilogue overlay

    const int tid = threadIdx.x;
    const int w = tid >> 6;        // wave 0..7: z-cols g*256 + [w*32, w*32+32)
    const int lane = tid & 63;
    const int r0 = blockIdx.x * 32;

    for (int i = tid; i < 32 * SEQ; i += 512) tok[i] = inputs[r0 * SEQ + i];
    for (int i = tid; i < 32 * STRIDE_H; i += 512) hbuf[0][i] = 0;
    // stage Wh slices kk=0..LKK-1 into LDS (fragment-contiguous, 16 B per lane)
    for (int i = tid; i < LKK * 2048; i += 512) {
        int kk = i >> 11;
        int r = i & 2047;            // ntile*64 + l
        int ntile = r >> 6, l = r & 63;
        ((uint4*)whlds)[i] = *(const uint4*)(WhFrag + (((ntile << 4) + kk) << 9) + l * 8);
    }

    // Register-resident Wh B-fragments, kk = LKK..15  (4 gates x 13 x 4 regs = 208)
    bf16x8 Bf[4][RKK];
#pragma unroll
    for (int g = 0; g < 4; ++g)
#pragma unroll
        for (int kk = 0; kk < RKK; ++kk)
            Bf[g][kk] = *(const bf16x8*)(WhFrag + ((((g * 8 + w) << 4) + LKK + kk) << 9) + lane * 8);

    // C/D layout: col = lane&31, row = (reg&3) + 8*(reg>>2) + 4*(lane>>5)
    int rows[16];
#pragma unroll
    for (int i = 0; i < 16; ++i) rows[i] = (i & 3) + 8 * (i >> 2) + 4 * (lane >> 5);

    floatx16 c_st;
#pragma unroll
    for (int i = 0; i < 16; ++i) c_st[i] = 0.f;

    __syncthreads();

    const float L2E = 1.4426950408889634f;
    const int abase = (lane & 31) * STRIDE_H + ((lane >> 5) << 3);
    const int hcol = (w << 5) + (lane & 31);
    int cur = 0;

#pragma unroll 1
    for (int t = 0; t < SEQ; ++t) {
        // ---- issue gather: 16 independent 8-B loads (4 gates packed per row),
        //      consumed ~1500 cycles later at gate time ----
        uint2 gxp[16];
#pragma unroll
        for (int i = 0; i < 16; ++i) {
            int v = tok[rows[i] * SEQ + t];
            gxp[i] = *(const uint2*)(WxBp + (v << 10) + (hcol << 2));
        }

        // ---- h @ Wh from C=0: kk=0..2 B-frags from LDS, kk=3..15 from registers ----
        floatx16 acc[4];
#pragma unroll
        for (int g = 0; g < 4; ++g)
#pragma unroll
            for (int i = 0; i < 16; ++i) acc[g][i] = 0.f;

        const unsigned short* hb = &hbuf[cur][0];
#pragma unroll
        for (int kk = 0; kk < LKK; ++kk) {
            bf16x8 af = *(const bf16x8*)(hb + abase + kk * 16);
#pragma unroll
            for (int g = 0; g < 4; ++g) {
                bf16x8 bf = *(const bf16x8*)(whlds + kk * 16384 + (g * 8 + w) * 512 + lane * 8);
                acc[g] = __builtin_amdgcn_mfma_f32_32x32x16_bf16(af, bf, acc[g], 0, 0, 0);
            }
        }
#pragma unroll
        for (int kk = 0; kk < RKK; ++kk) {
            bf16x8 af = *(const bf16x8*)(hb + abase + (LKK + kk) * 16);
            acc[0] = __builtin_amdgcn_mfma_f32_32x32x16_bf16(af, Bf[0][kk], acc[0], 0, 0, 0);
            acc[1] = __builtin_amdgcn_mfma_f32_32x32x16_bf16(af, Bf[1][kk], acc[1], 0, 0, 0);
            acc[2] = __builtin_amdgcn_mfma_f32_32x32x16_bf16(af, Bf[2][kk], acc[2], 0, 0, 0);
            acc[3] = __builtin_amdgcn_mfma_f32_32x32x16_bf16(af, Bf[3][kk], acc[3], 0, 0, 0);
        }

        // ---- gates (keras i,f,g,o); z = acc + unpack(gxp); c fp32 in regs ----
        unsigned short* hn = &hbuf[cur ^ 1][0];
#pragma unroll
        for (int i = 0; i < 16; ++i) {
            float zi = acc[0][i] + bflo(gxp[i].x);
            float zf = acc[1][i] + bfhi(gxp[i].x);
            float zg = acc[2][i] + bflo(gxp[i].y);
            float zo = acc[3][i] + bfhi(gxp[i].y);
            float si = __builtin_amdgcn_rcpf(1.f + __builtin_amdgcn_exp2f(-zi * L2E));
            float sf = __builtin_amdgcn_rcpf(1.f + __builtin_amdgcn_exp2f(-zf * L2E));
            float so = __builtin_amdgcn_rcpf(1.f + __builtin_amdgcn_exp2f(-zo * L2E));
            float tg = 1.f - 2.f * __builtin_amdgcn_rcpf(1.f + __builtin_amdgcn_exp2f(2.f * L2E * zg));
            float c = sf * c_st[i] + si * tg;
            c_st[i] = c;
            float tc = 1.f - 2.f * __builtin_amdgcn_rcpf(1.f + __builtin_amdgcn_exp2f(2.f * L2E * c));
            hn[rows[i] * STRIDE_H + hcol] = f2bf(so * tc);
        }
        __syncthreads();
        cur ^= 1;
    }
    // SEQ even -> final h in hbuf[0] (cur==0); logit overlays whlds.

    // ---- logits = h @ Wd + bd (waves 0..3, vocab n-tile = w) ----
    if (w < 4) {
        floatx16 accd;
        float bdv = bd[(w << 5) + (lane & 31)];
#pragma unroll
        for (int i = 0; i < 16; ++i) accd[i] = bdv;
        const unsigned short* hb = &hbuf[cur][0];
#pragma unroll
        for (int kk = 0; kk < 16; ++kk) {
            bf16x8 af = *(const bf16x8*)(hb + abase + kk * 16);
            bf16x8 bfd = *(const bf16x8*)(WdFrag + ((w * 16 + kk) << 9) + lane * 8);
            accd = __builtin_amdgcn_mfma_f32_32x32x16_bf16(af, bfd, accd, 0, 0, 0);
        }
#pragma unroll
        for (int i = 0; i < 16; ++i)
            logit[rows[i] * NUM_CHARS + (w << 5) + (lane & 31)] = accd[i];
    }
    __syncthreads();

    // ---- softmax: 16 threads per row, 8 cols each ----
    {
        int row = tid >> 4;
        int c0 = (tid & 15) << 3;
        float v[8];
        float m = -1e30f;
#pragma unroll
        for (int q = 0; q < 8; ++q) { v[q] = logit[row * NUM_CHARS + c0 + q]; m = fmaxf(m, v[q]); }
#pragma unroll
        for (int off = 1; off < 16; off <<= 1) m = fmaxf(m, __shfl_xor(m, off, 16));
        float s = 0.f;
#pragma unroll
        for (int q = 0; q < 8; ++q) { v[q] = __builtin_amdgcn_exp2f((v[q] - m) * L2E); s += v[q]; }
#pragma unroll
        for (int off = 1; off < 16; off <<= 1) s += __shfl_xor(s, off, 16);
        float inv = __builtin_amdgcn_rcpf(s);
        float* op = out + (size_t)(r0 + row) * NUM_CHARS + c0;
#pragma unroll
        for (int q = 0; q < 8; ++q) op[q] = v[q] * inv;
    }
}

extern "C" void kernel_launch(void* const* d_in, const int* in_sizes, int n_in,
                              void* d_out, int out_size, void* d_ws, size_t ws_size,
                              hipStream_t stream) {
    const int*   inputs = (const int*)d_in[0];
    const float* Wx = (const float*)d_in[1];
    const float* Wh = (const float*)d_in[2];
    const float* b  = (const float*)d_in[3];
    const float* Wd = (const float*)d_in[4];
    const float* bd = (const float*)d_in[5];
    float* out = (float*)d_out;

    unsigned short* WhFrag = (unsigned short*)d_ws;                         // 512 KB
    unsigned short* WxBp   = (unsigned short*)((char*)d_ws + (512 << 10));  // 256 KB
    unsigned short* WdFrag = (unsigned short*)((char*)d_ws + (768 << 10));  // 64 KB

    prep_wh <<<262144 / 256, 256, 0, stream>>>(Wh, WhFrag);
    prep_wxb<<<131072 / 256, 256, 0, stream>>>(Wx, b, WxBp);
    prep_wd <<< 32768 / 256, 256, 0, stream>>>(Wd, WdFrag);
    lstm_main<<<256, 512, 0, stream>>>(inputs, WhFrag, WxBp, WdFrag, bd, out);
}

// Round 5
// 577.262 us; speedup vs baseline: 1.4567x; 1.0382x over previous
//
#include <hip/hip_runtime.h>
#include <stdint.h>

#define NUM_CHARS 128
#define BATCH 8192
#define SEQ 40
#define HIDDEN 256
#define ZDIM 1024 /* 4*HIDDEN */
#define STRIDE_H 264 /* padded bf16 row stride for h in LDS */
#define LKK 4      /* K-slices served from LDS (kk = 0..3), 128 KB */
#define AKK 4      /* K-slices register(AGPR)-resident (kk = 4..7), 64 AGPRs */
/* kk = 8..15 streamed from L2 through a 2-deep register window */

typedef __bf16 bf16x8 __attribute__((ext_vector_type(8)));
typedef float floatx16 __attribute__((ext_vector_type(16)));

// MFMA via inline asm so B (and C/D) can be pinned to AGPRs; the intrinsic
// path let the compiler rematerialize B-loads from global every step.
#define MFMA_AA(acc, af, bf) \
    asm("v_mfma_f32_32x32x16_bf16 %0, %1, %2, %0" : "+a"(acc) : "v"(af), "a"(bf))
#define MFMA_AV(acc, af, bf) \
    asm("v_mfma_f32_32x32x16_bf16 %0, %1, %2, %0" : "+a"(acc) : "v"(af), "v"(bf))
#define PIN_A(x) asm("" : "+a"(x))
// VALU(accvgpr_write) -> MFMA srcC hazard
#define HAZ_PRE(a0,a1,a2,a3) \
    asm volatile("s_nop 4" : "+a"(a0), "+a"(a1), "+a"(a2), "+a"(a3))
// MFMA(8-pass) write -> accvgpr_read hazard
#define HAZ_POST(a0,a1,a2,a3) \
    asm volatile("s_nop 7\n\ts_nop 7\n\ts_nop 3" : "+a"(a0), "+a"(a1), "+a"(a2), "+a"(a3))

__device__ __forceinline__ unsigned short f2bf(float f) {
    union { float f; uint32_t u; } v; v.f = f;
    uint32_t u = v.u;
    u += 0x7FFFu + ((u >> 16) & 1u); // RNE
    return (unsigned short)(u >> 16);
}
__device__ __forceinline__ float bfhi(uint32_t u) {
    union { uint32_t u; float f; } v; v.u = u & 0xFFFF0000u; return v.f;
}
__device__ __forceinline__ float bflo(uint32_t u) {
    union { uint32_t u; float f; } v; v.u = u << 16; return v.f;
}

// ---- prep kernels ----
// WhFrag[ntile(32)][kk(16)][lane(64)][j(8)] bf16 ; element = Wh[k][n],
// k = kk*16 + (lane>>5)*8 + j, n = ntile*32 + (lane&31)
__global__ void prep_wh(const float* __restrict__ Wh, unsigned short* __restrict__ out) {
    int idx = blockIdx.x * blockDim.x + threadIdx.x;
    int j = idx & 7;
    int lane = (idx >> 3) & 63;
    int kk = (idx >> 9) & 15;
    int ntile = idx >> 13;
    int k = kk * 16 + ((lane >> 5) << 3) + j;
    int n = (ntile << 5) + (lane & 31);
    out[idx] = f2bf(Wh[k * ZDIM + n]);
}

// WxBp[v][c(256)][g(4)] bf16, gate-interleaved: 4 gate values per row = one 8-B load
__global__ void prep_wxb(const float* __restrict__ Wx, const float* __restrict__ b,
                         unsigned short* __restrict__ out) {
    int idx = blockIdx.x * blockDim.x + threadIdx.x;
    int v = idx >> 10;
    int r = idx & 1023;
    int c = r >> 2, g = r & 3;
    int src = (g << 8) + c;
    out[idx] = f2bf(Wx[(v << 10) + src] + b[src]);
}

// WdFrag[ntile(4)][kk(16)][lane(64)][j(8)] bf16 ; element = Wd[k][n]
__global__ void prep_wd(const float* __restrict__ Wd, unsigned short* __restrict__ out) {
    int idx = blockIdx.x * blockDim.x + threadIdx.x;
    int j = idx & 7;
    int lane = (idx >> 3) & 63;
    int kk = (idx >> 9) & 15;
    int nt = idx >> 13;
    int k = kk * 16 + ((lane >> 5) << 3) + j;
    int n = (nt << 5) + (lane & 31);
    out[idx] = f2bf(Wd[k * NUM_CHARS + n]);
}

// ---- main kernel: 256 blocks x 512 threads (1 block/CU, 2 waves/SIMD,
//      256 unified regs/wave: 128 AGPR [acc 64 + Bf 64] + ~128 VGPR) ----
__global__ __launch_bounds__(512, 1) void lstm_main(
    const int* __restrict__ inputs, const unsigned short* __restrict__ WhFrag,
    const unsigned short* __restrict__ WxBp, const unsigned short* __restrict__ WdFrag,
    const float* __restrict__ bd, float* __restrict__ out)
{
    __shared__ unsigned short whlds[LKK * 32 * 512];  // 128 KB: Wh slices kk=0..3
    __shared__ unsigned short hbuf[32 * STRIDE_H];    // 16.9 KB, single-buffered h
    __shared__ int tok[32 * SEQ];                     //  5.1 KB   (total 150 KB)
    float* logit = (float*)&whlds[0];                 // 16 KB epilogue overlay

    const int tid = threadIdx.x;
    const int w = tid >> 6;        // wave 0..7: z-cols g*256 + [w*32, w*32+32)
    const int lane = tid & 63;
    const int r0 = blockIdx.x * 32;

    for (int i = tid; i < 32 * SEQ; i += 512) tok[i] = inputs[r0 * SEQ + i];
    for (int i = tid; i < 32 * STRIDE_H; i += 512) hbuf[i] = 0;
    // stage Wh slices kk=0..3 into LDS (fragment-contiguous)
    for (int i = tid; i < LKK * 2048; i += 512) {
        int kk = i >> 11;
        int r = i & 2047;            // ntile*64 + l
        int ntile = r >> 6, l = r & 63;
        ((uint4*)whlds)[i] = *(const uint4*)(WhFrag + (((ntile << 4) + kk) << 9) + l * 8);
    }

    // AGPR-resident Wh B-fragments, kk = 4..7 (4 gates x 4 slices x 4 regs = 64 AGPR)
    bf16x8 Bf[4][AKK];
#pragma unroll
    for (int g = 0; g < 4; ++g)
#pragma unroll
        for (int kk = 0; kk < AKK; ++kk) {
            Bf[g][kk] = *(const bf16x8*)(WhFrag + ((((g * 8 + w) << 4) + LKK + kk) << 9) + lane * 8);
            PIN_A(Bf[g][kk]);
        }

    // per-gate base pointers for the streamed fragments (kk = 8..15)
    const unsigned short* sgb[4];
#pragma unroll
    for (int g = 0; g < 4; ++g) sgb[g] = WhFrag + (g * 8 + w) * 8192 + lane * 8;

    floatx16 c_st;
#pragma unroll
    for (int i = 0; i < 16; ++i) c_st[i] = 0.f;

    __syncthreads();

    const float L2E = 1.4426950408889634f;
    const int abase = (lane & 31) * STRIDE_H + ((lane >> 5) << 3);
    const int hcol = (w << 5) + (lane & 31);
    const int rbase = (lane >> 5) << 2;  // rows[i] = (i&3) + 8*(i>>2) + rbase

#pragma unroll 1
    for (int t = 0; t < SEQ; ++t) {
        // ---- gather Wx[token]+b: 16 independent 8-B loads, consumed at gate time ----
        uint2 gxp[16];
#pragma unroll
        for (int i = 0; i < 16; ++i) {
            int row = (i & 3) + 8 * (i >> 2) + rbase;
            int v = tok[row * SEQ + t];
            gxp[i] = *(const uint2*)(WxBp + (v << 10) + (hcol << 2));
        }

        // ---- prologue of stream window: kk = 8, 9 ----
        bf16x8 wv[2][4];
#pragma unroll
        for (int g = 0; g < 4; ++g) {
            wv[0][g] = *(const bf16x8*)(sgb[g] + (8 << 9));
            wv[1][g] = *(const bf16x8*)(sgb[g] + (9 << 9));
        }

        floatx16 acc[4];
#pragma unroll
        for (int g = 0; g < 4; ++g)
#pragma unroll
            for (int i = 0; i < 16; ++i) acc[g][i] = 0.f;
        HAZ_PRE(acc[0], acc[1], acc[2], acc[3]);

        // ---- kk 0..3: B from LDS ----
#pragma unroll
        for (int kk = 0; kk < LKK; ++kk) {
            bf16x8 af = *(const bf16x8*)(hbuf + abase + kk * 16);
#pragma unroll
            for (int g = 0; g < 4; ++g) {
                bf16x8 bf = *(const bf16x8*)(whlds + kk * 16384 + (g * 8 + w) * 512 + lane * 8);
                MFMA_AV(acc[g], af, bf);
            }
        }
        // ---- kk 4..7: B from AGPR ----
#pragma unroll
        for (int kk = 0; kk < AKK; ++kk) {
            bf16x8 af = *(const bf16x8*)(hbuf + abase + (LKK + kk) * 16);
            MFMA_AA(acc[0], af, Bf[0][kk]);
            MFMA_AA(acc[1], af, Bf[1][kk]);
            MFMA_AA(acc[2], af, Bf[2][kk]);
            MFMA_AA(acc[3], af, Bf[3][kk]);
        }
        // ---- kk 8..15: B streamed from L2, 2-deep rolling window ----
#pragma unroll
        for (int kk = 8; kk < 16; ++kk) {
            const int s = kk & 1;
            bf16x8 af = *(const bf16x8*)(hbuf + abase + kk * 16);
            MFMA_AV(acc[0], af, wv[s][0]);
            MFMA_AV(acc[1], af, wv[s][1]);
            MFMA_AV(acc[2], af, wv[s][2]);
            MFMA_AV(acc[3], af, wv[s][3]);
            if (kk + 2 < 16) {
#pragma unroll
                for (int g = 0; g < 4; ++g)
                    wv[s][g] = *(const bf16x8*)(sgb[g] + ((kk + 2) << 9));
            }
        }
        HAZ_POST(acc[0], acc[1], acc[2], acc[3]);

        // ---- gates (keras i,f,g,o); z = acc + unpack(gxp); c fp32 in regs ----
        float ho[16];
#pragma unroll
        for (int i = 0; i < 16; ++i) {
            float zi = acc[0][i] + bflo(gxp[i].x);
            float zf = acc[1][i] + bfhi(gxp[i].x);
            float zg = acc[2][i] + bflo(gxp[i].y);
            float zo = acc[3][i] + bfhi(gxp[i].y);
            float si = __builtin_amdgcn_rcpf(1.f + __builtin_amdgcn_exp2f(-zi * L2E));
            float sf = __builtin_amdgcn_rcpf(1.f + __builtin_amdgcn_exp2f(-zf * L2E));
            float so = __builtin_amdgcn_rcpf(1.f + __builtin_amdgcn_exp2f(-zo * L2E));
            float tg = 1.f - 2.f * __builtin_amdgcn_rcpf(1.f + __builtin_amdgcn_exp2f(2.f * L2E * zg));
            float c = sf * c_st[i] + si * tg;
            c_st[i] = c;
            float tc = 1.f - 2.f * __builtin_amdgcn_rcpf(1.f + __builtin_amdgcn_exp2f(2.f * L2E * c));
            ho[i] = so * tc;
        }
        __syncthreads();   // all waves done reading old h
#pragma unroll
        for (int i = 0; i < 16; ++i) {
            int row = (i & 3) + 8 * (i >> 2) + rbase;
            hbuf[row * STRIDE_H + hcol] = f2bf(ho[i]);
        }
        __syncthreads();   // new h visible
    }

    // ---- logits = h @ Wd + bd (waves 0..3, vocab n-tile = w); overlay whlds ----
    if (w < 4) {
        floatx16 accd;
        float bdv = bd[(w << 5) + (lane & 31)];
#pragma unroll
        for (int i = 0; i < 16; ++i) accd[i] = bdv;
#pragma unroll
        for (int kk = 0; kk < 16; ++kk) {
            bf16x8 af = *(const bf16x8*)(hbuf + abase + kk * 16);
            bf16x8 bfd = *(const bf16x8*)(WdFrag + ((w * 16 + kk) << 9) + lane * 8);
            accd = __builtin_amdgcn_mfma_f32_32x32x16_bf16(af, bfd, accd, 0, 0, 0);
        }
#pragma unroll
        for (int i = 0; i < 16; ++i) {
            int row = (i & 3) + 8 * (i >> 2) + rbase;
            logit[row * NUM_CHARS + (w << 5) + (lane & 31)] = accd[i];
        }
    }
    __syncthreads();

    // ---- softmax: 16 threads per row, 8 cols each ----
    {
        int row = tid >> 4;
        int c0 = (tid & 15) << 3;
        float v[8];
        float m = -1e30f;
#pragma unroll
        for (int q = 0; q < 8; ++q) { v[q] = logit[row * NUM_CHARS + c0 + q]; m = fmaxf(m, v[q]); }
#pragma unroll
        for (int off = 1; off < 16; off <<= 1) m = fmaxf(m, __shfl_xor(m, off, 16));
        float s = 0.f;
#pragma unroll
        for (int q = 0; q < 8; ++q) { v[q] = __builtin_amdgcn_exp2f((v[q] - m) * L2E); s += v[q]; }
#pragma unroll
        for (int off = 1; off < 16; off <<= 1) s += __shfl_xor(s, off, 16);
        float inv = __builtin_amdgcn_rcpf(s);
        float* op = out + (size_t)(r0 + row) * NUM_CHARS + c0;
#pragma unroll
        for (int q = 0; q < 8; ++q) op[q] = v[q] * inv;
    }
}

extern "C" void kernel_launch(void* const* d_in, const int* in_sizes, int n_in,
                              void* d_out, int out_size, void* d_ws, size_t ws_size,
                              hipStream_t stream) {
    const int*   inputs = (const int*)d_in[0];
    const float* Wx = (const float*)d_in[1];
    const float* Wh = (const float*)d_in[2];
    const float* b  = (const float*)d_in[3];
    const float* Wd = (const float*)d_in[4];
    const float* bd = (const float*)d_in[5];
    float* out = (float*)d_out;

    unsigned short* WhFrag = (unsigned short*)d_ws;                         // 512 KB
    unsigned short* WxBp   = (unsigned short*)((char*)d_ws + (512 << 10));  // 256 KB
    unsigned short* WdFrag = (unsigned short*)((char*)d_ws + (768 << 10));  // 64 KB

    prep_wh <<<262144 / 256, 256, 0, stream>>>(Wh, WhFrag);
    prep_wxb<<<131072 / 256, 256, 0, stream>>>(Wx, b, WxBp);
    prep_wd <<< 32768 / 256, 256, 0, stream>>>(Wd, WdFrag);
    lstm_main<<<256, 512, 0, stream>>>(inputs, WhFrag, WxBp, WdFrag, bd, out);
}